// Round 9
// baseline (1541.088 us; speedup 1.0000x reference)
//
#include <hip/hip_runtime.h>
#include <hip/hip_bf16.h>

#define N_MOLS      64
#define N_CONFS_PER 10
#define A_ATOMS     40
#define N_CONFS     640
#define N_ATOMS     25600
#define N_EDGES     409600
#define D           256
#define NG          32
#define NLAYERS     4
#define MOLB        512
#define H_MOL       384
#define EDGE_CAP    1024
#define EB          64    // edge batch
#define SHBP        36    // sHb row stride (halfwords)
#define SEFP        260   // sEFs row stride (halfwords): rows r,r+4,r+8,r+12 -> banks +0,8,16,24
#define SRP         260   // padded fp32 LDS row stride (dwords)
#define TPB         768   // 12 waves

typedef __attribute__((ext_vector_type(8))) short bshort8;
typedef __attribute__((ext_vector_type(4))) float f32x4;

__device__ __forceinline__ float sspf(float x) {
    return fmaxf(x, 0.f) + log1pf(expf(-fabsf(x))) - 0.69314718055994531f;
}
__device__ __forceinline__ float b2f(short s) {
    union { unsigned u; float f; } u;
    u.u = ((unsigned)(unsigned short)s) << 16;
    return u.f;
}
__device__ __forceinline__ short f2b(float x) {
    __hip_bfloat16 h = __float2bfloat16(x);
    return *reinterpret_cast<short*>(&h);
}

// pack 8 consecutive fp32 -> bf16x8 fragment
__device__ __forceinline__ bshort8 cvt8(const float* __restrict__ p) {
    const float4 lo = *(const float4*)p;
    const float4 hi = *(const float4*)(p + 4);
    union { bshort8 s; __hip_bfloat16 h[8]; } u;
    u.h[0] = __float2bfloat16(lo.x); u.h[1] = __float2bfloat16(lo.y);
    u.h[2] = __float2bfloat16(lo.z); u.h[3] = __float2bfloat16(lo.w);
    u.h[4] = __float2bfloat16(hi.x); u.h[5] = __float2bfloat16(hi.y);
    u.h[6] = __float2bfloat16(hi.z); u.h[7] = __float2bfloat16(hi.w);
    return u.s;
}

// ---------------- weight prep: dense W[l][k][n] fp32 -> WT[mat][l][n][k] bf16 ----------------
__global__ __launch_bounds__(256) void k_prep(const float* __restrict__ Wn,
                                              const float* __restrict__ Wu1,
                                              const float* __restrict__ Wu2,
                                              __hip_bfloat16* __restrict__ WT) {
    int idx = blockIdx.x * 256 + threadIdx.x;       // 3*4*256*256
    int k = idx & 255;
    int n = (idx >> 8) & 255;
    int l = (idx >> 16) & 3;
    int mat = idx >> 18;
    const float* src = (mat == 0) ? Wn : (mat == 1) ? Wu1 : Wu2;
    WT[idx] = __float2bfloat16(src[((size_t)l * 256 + k) * 256 + n]);
}

// WT2[l][n][k] bf16 from We2[l][k][n]; We1T[l][t][m] bf16 from We1[l][m][t]
__global__ __launch_bounds__(256) void k_prep2(const float* __restrict__ We2,
                                               const float* __restrict__ We1,
                                               __hip_bfloat16* __restrict__ WT2,
                                               __hip_bfloat16* __restrict__ We1T) {
    int idx = blockIdx.x * 256 + threadIdx.x;       // 32768 + 4096
    if (idx < 32768) {
        int k = idx & 31;
        int n = (idx >> 5) & 255;
        int l = idx >> 13;
        WT2[idx] = __float2bfloat16(We2[((size_t)l * 32 + k) * 256 + n]);
    } else {
        int j = idx - 32768;
        int m = j & 31;
        int t = (j >> 5) & 31;
        int l = j >> 10;
        We1T[j] = __float2bfloat16(We1[((size_t)l * 32 + m) * 32 + t]);
    }
}

// ---------------- edge bucketing by conformer ----------------
__global__ __launch_bounds__(256) void k_scatter(const int* __restrict__ nbr,
                                                 unsigned* __restrict__ cursors,
                                                 unsigned* __restrict__ esort) {
    int e = blockIdx.x * 256 + threadIdx.x;
    if (e >= N_EDGES) return;
    int a0 = nbr[2 * e], a1 = nbr[2 * e + 1];
    int conf = a0 / A_ATOMS;
    int a0l = a0 - conf * A_ATOMS;
    int a1l = a1 - conf * A_ATOMS;
    unsigned r = atomicAdd(&cursors[conf], 1u);
    if (r < EDGE_CAP) esort[conf * EDGE_CAP + r] = (unsigned)((a0l << 6) | a1l);
}

// dense MFMA, 12-wave split: wave -> (mt = wv>>2, nt0 = (wv&3)*4), 4 n-tiles
__device__ __forceinline__ void mfma_dense12(const float* __restrict__ src,
                                             const __hip_bfloat16* __restrict__ WT,
                                             f32x4 acc[4], int lane, int mt, int nt0) {
    const int r = lane & 15, g = lane >> 4;
#pragma unroll
    for (int j = 0; j < 4; ++j) acc[j] = (f32x4){0.f, 0.f, 0.f, 0.f};
#pragma unroll 2
    for (int kt = 0; kt < 8; ++kt) {
        const int ko = kt * 32 + g * 8;
        bshort8 a = cvt8(&src[(mt * 16 + r) * SRP + ko]);
#pragma unroll
        for (int j = 0; j < 4; ++j) {
            bshort8 b = *(const bshort8*)&WT[((nt0 + j) * 16 + r) * 256 + ko];
            acc[j] = __builtin_amdgcn_mfma_f32_16x16x32_bf16(a, b, acc[j], 0, 0, 0);
        }
    }
}

// writeback: MODE 0: dst = acc+bias ; 1: dst = ssp(acc+bias) ; 2: dst += acc+bias
template <int MODE>
__device__ __forceinline__ void mfma_wb12(const f32x4 acc[4], float* __restrict__ dst,
                                          const float* __restrict__ bias,
                                          int lane, int mt, int nt0) {
    const int cc = lane & 15, g = lane >> 4;
    const int cr = g * 4;
    if (mt == 2 && g >= 2) return;   // rows 40..47 are padding
#pragma unroll
    for (int j = 0; j < 4; ++j) {
        const int col = (nt0 + j) * 16 + cc;
        const float bv = bias[col];
#pragma unroll
        for (int reg = 0; reg < 4; ++reg) {
            const int row = mt * 16 + cr + reg;
            float v = acc[j][reg] + bv;
            if (MODE == 1) v = sspf(v);
            if (MODE == 2) v += dst[row * SRP + col];
            dst[row * SRP + col] = v;
        }
    }
}

// ---------------- main per-conformer kernel: 768 threads, 12 waves ----------------
__global__ __launch_bounds__(TPB, 3) void k_main(
    const int* __restrict__ z, const float* __restrict__ xyz,
    const float* __restrict__ emb,
    const float* __restrict__ be1, const float* __restrict__ be2,
    const float* __restrict__ bn,
    const float* __restrict__ bu1, const float* __restrict__ bu2,
    const __hip_bfloat16* __restrict__ WT,
    const __hip_bfloat16* __restrict__ WT2,
    const __hip_bfloat16* __restrict__ We1T,
    const unsigned* __restrict__ cursors, const unsigned* __restrict__ esort,
    float* __restrict__ conf_fp)
{
    __shared__ float sR[48 * SRP];            // residual r (49.9KB)
    __shared__ float sB[48 * SRP];            // rn -> agg -> t (49.9KB)
    __shared__ short sEFs[EB * SEFP];         // ef batch bf16, stride-260 (33.3KB)
    __shared__ short sHb[2][EB * SHBP];       // h double-buffer bf16 (9.2KB)
    __shared__ float sDall[1152];             // scaled distances + zero pad (4.6KB)
    __shared__ unsigned sEdge[EDGE_CAP];      // packed edges (4KB)
    __shared__ unsigned short sCsr[2 * EDGE_CAP]; // CSR entries (src<<10)|edge (4KB)
    __shared__ int sPtr[A_ATOMS + 1];
    __shared__ int sDeg[A_ATOMS];
    __shared__ float sXYZ[A_ATOMS][3];
    __shared__ int sZ[A_ATOMS];

    const int tid  = threadIdx.x;
    const int lane = tid & 63;
    const int wv   = tid >> 6;        // 0..11
    const int c4   = lane << 2;
    const int conf = blockIdx.x;
    const int fr = lane & 15, fg = lane >> 4, g8 = (lane >> 4) << 3;
    const int mt_d  = wv >> 2;        // dense m-tile 0..2
    const int nt0_d = (wv & 3) * 4;   // dense first n-tile

    if (tid < A_ATOMS) {
        int ga = conf * A_ATOMS + tid;
        sZ[tid] = z[ga];
        sXYZ[tid][0] = xyz[ga * 3 + 0];
        sXYZ[tid][1] = xyz[ga * 3 + 1];
        sXYZ[tid][2] = xyz[ga * 3 + 2];
        sDeg[tid] = 0;
    }
    for (int i = tid; i < 8 * SRP; i += TPB) {   // zero pad rows 40..47
        sR[40 * SRP + i] = 0.f;
        sB[40 * SRP + i] = 0.f;
    }
    __syncthreads();
    {   // embedding init
        const int c = tid & 255, q = tid >> 8;
        for (int aa = q; aa < A_ATOMS; aa += 3)
            sR[aa * SRP + c] = emb[sZ[aa] * D + c];
    }
    int cnt = (int)cursors[conf];
    if (cnt > EDGE_CAP) cnt = EDGE_CAP;
    const unsigned* eptr = esort + conf * EDGE_CAP;
    for (int i = tid; i < cnt; i += TPB) {
        unsigned pe = eptr[i];
        sEdge[i] = pe;
        int a0l = (pe >> 6) & 63, a1l = pe & 63;
        float dx = sXYZ[a0l][0] - sXYZ[a1l][0];
        float dy = sXYZ[a0l][1] - sXYZ[a1l][1];
        float dz = sXYZ[a0l][2] - sXYZ[a1l][2];
        sDall[i] = sqrtf(dx * dx + dy * dy + dz * dz) * (31.0f / 5.0f);
        atomicAdd(&sDeg[a0l], 1);
        atomicAdd(&sDeg[a1l], 1);
    }
    for (int i = cnt + tid; i < 1152; i += TPB) sDall[i] = 0.f;
    __syncthreads();
    if (tid == 0) {
        int s = 0;
        for (int a = 0; a < A_ATOMS; ++a) { sPtr[a] = s; s += sDeg[a]; }
        sPtr[A_ATOMS] = s;
    }
    __syncthreads();
    // ordered CSR fill: thread a scans all edges in order (entries sorted by edge id)
    if (tid < A_ATOMS) {
        int pos = sPtr[tid];
        for (int i = 0; i < cnt; ++i) {
            unsigned pe = sEdge[i];
            int a0l = (pe >> 6) & 63, a1l = pe & 63;
            if (a0l == tid) sCsr[pos++] = (unsigned short)((a1l << 10) | i);
            if (a1l == tid) sCsr[pos++] = (unsigned short)((a0l << 10) | i);
        }
    }

    const int NB = (cnt + EB - 1) / EB;

    for (int l = 0; l < NLAYERS; ++l) {
        __syncthreads();
        // ---- M1: sB = r @ Wn + bn
        {
            f32x4 acc[4];
            mfma_dense12(sR, WT + ((size_t)(0 * 4 + l) << 16), acc, lane, mt_d, nt0_d);
            mfma_wb12<0>(acc, sB, bn + l * D, lane, mt_d, nt0_d);
        }
        __syncthreads();
        // ---- edge phase: 2-barrier pipelined batches of 64
        float4 agg[4];
        int cur[4], endr[4];
#pragma unroll
        for (int k = 0; k < 4; ++k) {
            agg[k] = make_float4(0.f, 0.f, 0.f, 0.f);
            const int row = wv + 12 * k;
            cur[k]  = (row < A_ATOMS) ? sPtr[row] : 0;
            endr[k] = (row < A_ATOMS) ? sPtr[row + 1] : 0;
        }
        // per-layer hoisted fragments (role-dependent)
        bshort8 bf0, bf1;
        float   bb0, bb1;
        if (wv < 8) {   // P4: n-tiles 2wv, 2wv+1
            bf0 = *(const bshort8*)&WT2[(size_t)l * 8192 + ((2 * wv + 0) * 16 + fr) * 32 + g8];
            bf1 = *(const bshort8*)&WT2[(size_t)l * 8192 + ((2 * wv + 1) * 16 + fr) * 32 + g8];
            bb0 = be2[l * D + (2 * wv + 0) * 16 + fr];
            bb1 = be2[l * D + (2 * wv + 1) * 16 + fr];
        } else {        // X2: m-tile wv-8, both t-tiles
            bf0 = *(const bshort8*)&We1T[(size_t)l * 1024 + (0 * 16 + fr) * 32 + g8];
            bf1 = *(const bshort8*)&We1T[(size_t)l * 1024 + (1 * 16 + fr) * 32 + g8];
            bb0 = be1[l * NG + 0 * 16 + fr];
            bb1 = be1[l * NG + 1 * 16 + fr];
        }
        // prologue: X2 for batch 0 -> sHb[0]
        if (wv >= 8 && NB > 0) {
            const int mtx = wv - 8;
            const float dd = sDall[mtx * 16 + fr];
            union { bshort8 v; unsigned short h[8]; } ua;
#pragma unroll
            for (int j = 0; j < 8; ++j) {
                const float u = dd - (float)(g8 + j);
                ua.h[j] = (unsigned short)f2b(expf(-0.5f * u * u));
            }
            f32x4 c0 = (f32x4){0.f, 0.f, 0.f, 0.f};
            c0 = __builtin_amdgcn_mfma_f32_16x16x32_bf16(ua.v, bf0, c0, 0, 0, 0);
            f32x4 c1 = (f32x4){0.f, 0.f, 0.f, 0.f};
            c1 = __builtin_amdgcn_mfma_f32_16x16x32_bf16(ua.v, bf1, c1, 0, 0, 0);
#pragma unroll
            for (int reg = 0; reg < 4; ++reg) {
                const int erow = mtx * 16 + fg * 4 + reg;
                sHb[0][erow * SHBP +  0 + fr] = f2b(sspf(c0[reg] + bb0));
                sHb[0][erow * SHBP + 16 + fr] = f2b(sspf(c1[reg] + bb1));
            }
        }
        __syncthreads();
        for (int b = 0; b < NB; ++b) {
            const int base = b * EB;
            // phase1: P4(b) on waves 0-7  ||  X2(b+1) on waves 8-11
            if (wv < 8) {
                const short* __restrict__ hb = sHb[b & 1];
#pragma unroll
                for (int mt = 0; mt < 4; ++mt) {
                    union { bshort8 v; short4 s[2]; } af;
                    af.s[0] = *(const short4*)&hb[(mt * 16 + fr) * SHBP + g8];
                    af.s[1] = *(const short4*)&hb[(mt * 16 + fr) * SHBP + g8 + 4];
                    f32x4 c0 = (f32x4){0.f, 0.f, 0.f, 0.f};
                    c0 = __builtin_amdgcn_mfma_f32_16x16x32_bf16(af.v, bf0, c0, 0, 0, 0);
                    f32x4 c1 = (f32x4){0.f, 0.f, 0.f, 0.f};
                    c1 = __builtin_amdgcn_mfma_f32_16x16x32_bf16(af.v, bf1, c1, 0, 0, 0);
#pragma unroll
                    for (int reg = 0; reg < 4; ++reg) {
                        const int erow = mt * 16 + fg * 4 + reg;
                        sEFs[erow * SEFP + (2 * wv + 0) * 16 + fr] = f2b(c0[reg] + bb0);
                        sEFs[erow * SEFP + (2 * wv + 1) * 16 + fr] = f2b(c1[reg] + bb1);
                    }
                }
            } else if (b + 1 < NB) {
                const int nbase = (b + 1) * EB;
                short* __restrict__ hb = sHb[(b + 1) & 1];
                const int mtx = wv - 8;
                const float dd = sDall[nbase + mtx * 16 + fr];
                union { bshort8 v; unsigned short h[8]; } ua;
#pragma unroll
                for (int j = 0; j < 8; ++j) {
                    const float u = dd - (float)(g8 + j);
                    ua.h[j] = (unsigned short)f2b(expf(-0.5f * u * u));
                }
                f32x4 c0 = (f32x4){0.f, 0.f, 0.f, 0.f};
                c0 = __builtin_amdgcn_mfma_f32_16x16x32_bf16(ua.v, bf0, c0, 0, 0, 0);
                f32x4 c1 = (f32x4){0.f, 0.f, 0.f, 0.f};
                c1 = __builtin_amdgcn_mfma_f32_16x16x32_bf16(ua.v, bf1, c1, 0, 0, 0);
#pragma unroll
                for (int reg = 0; reg < 4; ++reg) {
                    const int erow = mtx * 16 + fg * 4 + reg;
                    hb[erow * SHBP +  0 + fr] = f2b(sspf(c0[reg] + bb0));
                    hb[erow * SHBP + 16 + fr] = f2b(sspf(c1[reg] + bb1));
                }
            }
            __syncthreads();
            // phase2: P5 gather for batch b (all 12 waves, CSR cursor window)
            {
                const int elim = base + EB;
#pragma unroll
                for (int k = 0; k < 4; ++k) {
                    const int row = wv + 12 * k;
                    if (row >= A_ATOMS) break;
                    int cc = cur[k];
                    const int ce = endr[k];
                    while (cc < ce) {
                        const int ent = (int)sCsr[cc];
                        const int e = ent & 1023;
                        if (e >= elim) break;
                        const int src = ent >> 10;
                        const short4 f4 = *(const short4*)&sEFs[(e - base) * SEFP + c4];
                        const float4 r4 = *(const float4*)&sB[src * SRP + c4];
                        agg[k].x = fmaf(b2f(f4.x), r4.x, agg[k].x);
                        agg[k].y = fmaf(b2f(f4.y), r4.y, agg[k].y);
                        agg[k].z = fmaf(b2f(f4.z), r4.z, agg[k].z);
                        agg[k].w = fmaf(b2f(f4.w), r4.w, agg[k].w);
                        ++cc;
                    }
                    cur[k] = cc;
                }
            }
            __syncthreads();
        }
        // agg -> sB (rn dead)
#pragma unroll
        for (int k = 0; k < 4; ++k) {
            const int row = wv + 12 * k;
            if (row < A_ATOMS) *(float4*)&sB[row * SRP + c4] = agg[k];
        }
        __syncthreads();
        // ---- M2: sB = ssp(agg @ Wu1 + bu1)  (in-place: sync between acc and wb)
        {
            f32x4 acc[4];
            mfma_dense12(sB, WT + ((size_t)(1 * 4 + l) << 16), acc, lane, mt_d, nt0_d);
            __syncthreads();
            mfma_wb12<1>(acc, sB, bu1 + l * D, lane, mt_d, nt0_d);
        }
        __syncthreads();
        // ---- M3: sR += t @ Wu2 + bu2
        {
            f32x4 acc[4];
            mfma_dense12(sB, WT + ((size_t)(2 * 4 + l) << 16), acc, lane, mt_d, nt0_d);
            mfma_wb12<2>(acc, sR, bu2 + l * D, lane, mt_d, nt0_d);
        }
    }
    __syncthreads();
    if (tid < D) {
        float s = 0.f;
#pragma unroll
        for (int a = 0; a < A_ATOMS; ++a) s += sR[a * SRP + tid];
        conf_fp[conf * D + tid] = s;
    }
}

// ---------------- per-conformer molecular MLP + Boltzmann-weighted reduce ----------------
__global__ __launch_bounds__(512) void k_mol(
    const float* __restrict__ conf_fp,
    const float* __restrict__ Wm1, const float* __restrict__ bm1,
    const float* __restrict__ Wm2, const float* __restrict__ bm2,
    const float* __restrict__ boltz, float* __restrict__ mol_fp)
{
    __shared__ float cf[D];
    __shared__ float t[H_MOL];
    const int conf = blockIdx.x;
    const int tid = threadIdx.x;
    if (tid < D) cf[tid] = conf_fp[conf * D + tid];
    __syncthreads();
    if (tid < H_MOL) {
        float s = bm1[tid];
        for (int k = 0; k < D; k += 4) {
            const float4 v = *(const float4*)&cf[k];
            s = fmaf(v.x, Wm1[(k + 0) * H_MOL + tid], s);
            s = fmaf(v.y, Wm1[(k + 1) * H_MOL + tid], s);
            s = fmaf(v.z, Wm1[(k + 2) * H_MOL + tid], s);
            s = fmaf(v.w, Wm1[(k + 3) * H_MOL + tid], s);
        }
        t[tid] = sspf(s);
    }
    __syncthreads();
    {
        const int m = tid;
        float s = bm2[m];
        for (int h = 0; h < H_MOL; h += 4) {
            const float4 v = *(const float4*)&t[h];
            s = fmaf(v.x, Wm2[(h + 0) * MOLB + m], s);
            s = fmaf(v.y, Wm2[(h + 1) * MOLB + m], s);
            s = fmaf(v.z, Wm2[(h + 2) * MOLB + m], s);
            s = fmaf(v.w, Wm2[(h + 3) * MOLB + m], s);
        }
        atomicAdd(&mol_fp[(conf / N_CONFS_PER) * MOLB + m], s * boltz[conf]);
    }
}

// ---------------- final readout MLP + sigmoid ----------------
__global__ __launch_bounds__(256) void k_final(
    const float* __restrict__ mol_fp,
    const float* __restrict__ Wr1, const float* __restrict__ br1,
    const float* __restrict__ Wr2, const float* __restrict__ br2,
    float* __restrict__ out)
{
    __shared__ float mf[MOLB];
    __shared__ float t2[D];
    __shared__ float red[4];
    const int mol = blockIdx.x, tid = threadIdx.x;
    mf[tid]       = mol_fp[mol * MOLB + tid];
    mf[tid + 256] = mol_fp[mol * MOLB + tid + 256];
    __syncthreads();
    {
        float s = br1[tid];
        for (int k = 0; k < MOLB; k += 4) {
            const float4 v = *(const float4*)&mf[k];
            s = fmaf(v.x, Wr1[(k + 0) * D + tid], s);
            s = fmaf(v.y, Wr1[(k + 1) * D + tid], s);
            s = fmaf(v.z, Wr1[(k + 2) * D + tid], s);
            s = fmaf(v.w, Wr1[(k + 3) * D + tid], s);
        }
        t2[tid] = sspf(s);
    }
    __syncthreads();
    float p = t2[tid] * Wr2[tid];
#pragma unroll
    for (int o = 32; o > 0; o >>= 1) p += __shfl_down(p, o);
    if ((tid & 63) == 0) red[tid >> 6] = p;
    __syncthreads();
    if (tid == 0) {
        float logit = red[0] + red[1] + red[2] + red[3] + br2[0];
        out[mol] = 1.f / (1.f + expf(-logit));
    }
}

extern "C" void kernel_launch(void* const* d_in, const int* in_sizes, int n_in,
                              void* d_out, int out_size, void* d_ws, size_t ws_size,
                              hipStream_t stream)
{
    const int*   z     = (const int*)d_in[0];
    const float* xyz   = (const float*)d_in[1];
    const int*   nbr   = (const int*)d_in[2];
    const float* boltz = (const float*)d_in[3];
    const float* emb   = (const float*)d_in[4];
    const float* We1   = (const float*)d_in[5];
    const float* be1   = (const float*)d_in[6];
    const float* We2   = (const float*)d_in[7];
    const float* be2   = (const float*)d_in[8];
    const float* Wn    = (const float*)d_in[9];
    const float* bn    = (const float*)d_in[10];
    const float* Wu1   = (const float*)d_in[11];
    const float* bu1   = (const float*)d_in[12];
    const float* Wu2   = (const float*)d_in[13];
    const float* bu2   = (const float*)d_in[14];
    const float* Wm1   = (const float*)d_in[15];
    const float* bm1   = (const float*)d_in[16];
    const float* Wm2   = (const float*)d_in[17];
    const float* bm2   = (const float*)d_in[18];
    const float* Wr1   = (const float*)d_in[19];
    const float* br1   = (const float*)d_in[20];
    const float* Wr2   = (const float*)d_in[21];
    const float* br2   = (const float*)d_in[22];

    char* ws = (char*)d_ws;
    unsigned* cursors        = (unsigned*)ws;                   // 2560 B
    float*    mol_fp         = (float*)(ws + 2560);             // 131072 B -> 133632
    unsigned* esort          = (unsigned*)(ws + 133632);        // 2621440 B -> 2755072
    float*    conf_fp        = (float*)(ws + 2755072);          // 655360 B -> 3410432
    __hip_bfloat16* WT       = (__hip_bfloat16*)(ws + 3410432); // 1572864 B -> 4983296
    __hip_bfloat16* WT2      = (__hip_bfloat16*)(ws + 4983296); // 65536 B -> 5048832
    __hip_bfloat16* We1T     = (__hip_bfloat16*)(ws + 5048832); // 8192 B -> 5057024

    hipMemsetAsync(cursors, 0, 2560 + 131072, stream);          // cursors + mol_fp
    k_prep<<<3072, 256, 0, stream>>>(Wn, Wu1, Wu2, WT);
    k_prep2<<<144, 256, 0, stream>>>(We2, We1, WT2, We1T);
    k_scatter<<<(N_EDGES + 255) / 256, 256, 0, stream>>>(nbr, cursors, esort);
    k_main<<<N_CONFS, TPB, 0, stream>>>(z, xyz, emb, be1, be2, bn,
                                        bu1, bu2, WT, WT2, We1T, cursors, esort, conf_fp);
    k_mol<<<N_CONFS, 512, 0, stream>>>(conf_fp, Wm1, bm1, Wm2, bm2, boltz, mol_fp);
    k_final<<<N_MOLS, 256, 0, stream>>>(mol_fp, Wr1, br1, Wr2, br2, (float*)d_out);
}

// Round 10
// 1296.933 us; speedup vs baseline: 1.1883x; 1.1883x over previous
//
#include <hip/hip_runtime.h>
#include <hip/hip_bf16.h>

#define N_MOLS      64
#define N_CONFS_PER 10
#define A_ATOMS     40
#define N_CONFS     640
#define N_ATOMS     25600
#define N_EDGES     409600
#define D           256
#define NG          32
#define NLAYERS     4
#define MOLB        512
#define H_MOL       384
#define EDGE_CAP    1024
#define EB          64    // edge batch
#define NBMAX       16    // max batches (EDGE_CAP/EB)
#define SHBP        36    // sHb row stride (halfwords)
#define SEFP        260   // sEFs row stride (halfwords)
#define SRP         260   // padded fp32 LDS row stride (dwords)
#define TPB         512   // 8 waves (R6's proven occupancy sweet spot)

typedef __attribute__((ext_vector_type(8))) short bshort8;
typedef __attribute__((ext_vector_type(4))) float f32x4;

__device__ __forceinline__ float sspf(float x) {
    return fmaxf(x, 0.f) + log1pf(expf(-fabsf(x))) - 0.69314718055994531f;
}
__device__ __forceinline__ float b2f(short s) {
    union { unsigned u; float f; } u;
    u.u = ((unsigned)(unsigned short)s) << 16;
    return u.f;
}
__device__ __forceinline__ short f2b(float x) {
    __hip_bfloat16 h = __float2bfloat16(x);
    return *reinterpret_cast<short*>(&h);
}

// pack 8 consecutive fp32 -> bf16x8 fragment
__device__ __forceinline__ bshort8 cvt8(const float* __restrict__ p) {
    const float4 lo = *(const float4*)p;
    const float4 hi = *(const float4*)(p + 4);
    union { bshort8 s; __hip_bfloat16 h[8]; } u;
    u.h[0] = __float2bfloat16(lo.x); u.h[1] = __float2bfloat16(lo.y);
    u.h[2] = __float2bfloat16(lo.z); u.h[3] = __float2bfloat16(lo.w);
    u.h[4] = __float2bfloat16(hi.x); u.h[5] = __float2bfloat16(hi.y);
    u.h[6] = __float2bfloat16(hi.z); u.h[7] = __float2bfloat16(hi.w);
    return u.s;
}

// ---------------- weight prep: dense W[l][k][n] fp32 -> WT[mat][l][n][k] bf16 ----------------
__global__ __launch_bounds__(256) void k_prep(const float* __restrict__ Wn,
                                              const float* __restrict__ Wu1,
                                              const float* __restrict__ Wu2,
                                              __hip_bfloat16* __restrict__ WT) {
    int idx = blockIdx.x * 256 + threadIdx.x;       // 3*4*256*256
    int k = idx & 255;
    int n = (idx >> 8) & 255;
    int l = (idx >> 16) & 3;
    int mat = idx >> 18;
    const float* src = (mat == 0) ? Wn : (mat == 1) ? Wu1 : Wu2;
    WT[idx] = __float2bfloat16(src[((size_t)l * 256 + k) * 256 + n]);
}

// WT2[l][n][k] bf16 from We2[l][k][n]; We1T[l][t][m] bf16 from We1[l][m][t]
__global__ __launch_bounds__(256) void k_prep2(const float* __restrict__ We2,
                                               const float* __restrict__ We1,
                                               __hip_bfloat16* __restrict__ WT2,
                                               __hip_bfloat16* __restrict__ We1T) {
    int idx = blockIdx.x * 256 + threadIdx.x;       // 32768 + 4096
    if (idx < 32768) {
        int k = idx & 31;
        int n = (idx >> 5) & 255;
        int l = idx >> 13;
        WT2[idx] = __float2bfloat16(We2[((size_t)l * 32 + k) * 256 + n]);
    } else {
        int j = idx - 32768;
        int m = j & 31;
        int t = (j >> 5) & 31;
        int l = j >> 10;
        We1T[j] = __float2bfloat16(We1[((size_t)l * 32 + m) * 32 + t]);
    }
}

// ---------------- edge bucketing by conformer ----------------
__global__ __launch_bounds__(256) void k_scatter(const int* __restrict__ nbr,
                                                 unsigned* __restrict__ cursors,
                                                 unsigned* __restrict__ esort) {
    int e = blockIdx.x * 256 + threadIdx.x;
    if (e >= N_EDGES) return;
    int a0 = nbr[2 * e], a1 = nbr[2 * e + 1];
    int conf = a0 / A_ATOMS;
    int a0l = a0 - conf * A_ATOMS;
    int a1l = a1 - conf * A_ATOMS;
    unsigned r = atomicAdd(&cursors[conf], 1u);
    if (r < EDGE_CAP) esort[conf * EDGE_CAP + r] = (unsigned)((a0l << 6) | a1l);
}

// dense MFMA, 8-wave split: wave -> all 3 m-tiles x n-tiles {2wv, 2wv+1}
__device__ __forceinline__ void mfma_dense8(const float* __restrict__ src,
                                            const __hip_bfloat16* __restrict__ WT,
                                            f32x4 acc[3][2], int lane, int wv) {
    const int r = lane & 15, g = lane >> 4;
#pragma unroll
    for (int mt = 0; mt < 3; ++mt)
#pragma unroll
        for (int j = 0; j < 2; ++j) acc[mt][j] = (f32x4){0.f, 0.f, 0.f, 0.f};
#pragma unroll 2
    for (int kt = 0; kt < 8; ++kt) {
        const int ko = kt * 32 + g * 8;
        bshort8 a0 = cvt8(&src[(0 * 16 + r) * SRP + ko]);
        bshort8 a1 = cvt8(&src[(1 * 16 + r) * SRP + ko]);
        bshort8 a2 = cvt8(&src[(2 * 16 + r) * SRP + ko]);
#pragma unroll
        for (int j = 0; j < 2; ++j) {
            const int nt = wv * 2 + j;
            bshort8 b = *(const bshort8*)&WT[(nt * 16 + r) * 256 + ko];
            acc[0][j] = __builtin_amdgcn_mfma_f32_16x16x32_bf16(a0, b, acc[0][j], 0, 0, 0);
            acc[1][j] = __builtin_amdgcn_mfma_f32_16x16x32_bf16(a1, b, acc[1][j], 0, 0, 0);
            acc[2][j] = __builtin_amdgcn_mfma_f32_16x16x32_bf16(a2, b, acc[2][j], 0, 0, 0);
        }
    }
}

// writeback: MODE 0: dst = acc+bias ; 1: dst = ssp(acc+bias) ; 2: dst += acc+bias
template <int MODE>
__device__ __forceinline__ void mfma_wb8(const f32x4 acc[3][2], float* __restrict__ dst,
                                         const float* __restrict__ bias, int lane, int wv) {
    const int cc = lane & 15, g = lane >> 4;
    const int cr = g * 4;
#pragma unroll
    for (int j = 0; j < 2; ++j) {
        const int col = (wv * 2 + j) * 16 + cc;
        const float bv = bias[col];
#pragma unroll
        for (int mt = 0; mt < 3; ++mt) {
            if (mt == 2 && g >= 2) continue;   // rows 40..47 are padding
#pragma unroll
            for (int reg = 0; reg < 4; ++reg) {
                const int row = mt * 16 + cr + reg;
                float v = acc[mt][j][reg] + bv;
                if (MODE == 1) v = sspf(v);
                if (MODE == 2) v += dst[row * SRP + col];
                dst[row * SRP + col] = v;
            }
        }
    }
}

// ---------------- main per-conformer kernel: 512 threads, 8 waves ----------------
__global__ __launch_bounds__(TPB, 2) void k_main(
    const int* __restrict__ z, const float* __restrict__ xyz,
    const float* __restrict__ emb,
    const float* __restrict__ be1, const float* __restrict__ be2,
    const float* __restrict__ bn,
    const float* __restrict__ bu1, const float* __restrict__ bu2,
    const __hip_bfloat16* __restrict__ WT,
    const __hip_bfloat16* __restrict__ WT2,
    const __hip_bfloat16* __restrict__ We1T,
    const unsigned* __restrict__ cursors, const unsigned* __restrict__ esort,
    float* __restrict__ conf_fp)
{
    __shared__ float sR[48 * SRP];            // residual r (49.9KB)
    __shared__ float sB[48 * SRP];            // rn -> agg -> t (49.9KB)
    __shared__ short sEFs[EB * SEFP];         // ef batch bf16, stride-260 (33.3KB)
    __shared__ short sHb[2][EB * SHBP];       // h double-buffer bf16 (9.2KB)
    __shared__ float sDall[1152];             // scaled distances + zero pad (4.6KB)
    __shared__ unsigned sEdge[EDGE_CAP];      // packed edges (4KB)
    __shared__ unsigned short sCsr[2 * EDGE_CAP];       // (src<<10)|edge, edge-sorted (4KB)
    __shared__ unsigned short sWin[A_ATOMS * (NBMAX + 1)]; // per-(atom,batch) cursor (1.4KB)
    __shared__ int sPtr[A_ATOMS + 1];
    __shared__ int sDeg[A_ATOMS];
    __shared__ float sXYZ[A_ATOMS][3];
    __shared__ int sZ[A_ATOMS];

    const int tid  = threadIdx.x;
    const int lane = tid & 63;
    const int wv   = tid >> 6;        // 0..7
    const int c4   = lane << 2;
    const int conf = blockIdx.x;
    const int fr = lane & 15, fg = lane >> 4, g8 = (lane >> 4) << 3;
    const int mtx = wv & 3;           // X2 m-tile
    const int ttx = wv >> 2;          // X2 t-tile

    if (tid < A_ATOMS) {
        int ga = conf * A_ATOMS + tid;
        sZ[tid] = z[ga];
        sXYZ[tid][0] = xyz[ga * 3 + 0];
        sXYZ[tid][1] = xyz[ga * 3 + 1];
        sXYZ[tid][2] = xyz[ga * 3 + 2];
        sDeg[tid] = 0;
    }
    for (int i = tid; i < 8 * SRP; i += TPB) {   // zero pad rows 40..47
        sR[40 * SRP + i] = 0.f;
        sB[40 * SRP + i] = 0.f;
    }
    __syncthreads();
    {   // embedding init: half q handles rows q, q+2, ...
        const int c = tid & 255, q = tid >> 8;
        for (int aa = q; aa < A_ATOMS; aa += 2)
            sR[aa * SRP + c] = emb[sZ[aa] * D + c];
    }
    int cnt = (int)cursors[conf];
    if (cnt > EDGE_CAP) cnt = EDGE_CAP;
    const unsigned* eptr = esort + conf * EDGE_CAP;
    for (int i = tid; i < cnt; i += TPB) {
        unsigned pe = eptr[i];
        sEdge[i] = pe;
        int a0l = (pe >> 6) & 63, a1l = pe & 63;
        float dx = sXYZ[a0l][0] - sXYZ[a1l][0];
        float dy = sXYZ[a0l][1] - sXYZ[a1l][1];
        float dz = sXYZ[a0l][2] - sXYZ[a1l][2];
        sDall[i] = sqrtf(dx * dx + dy * dy + dz * dz) * (31.0f / 5.0f);
        atomicAdd(&sDeg[a0l], 1);
        atomicAdd(&sDeg[a1l], 1);
    }
    for (int i = cnt + tid; i < 1152; i += TPB) sDall[i] = 0.f;
    __syncthreads();
    if (tid == 0) {
        int s = 0;
        for (int a = 0; a < A_ATOMS; ++a) { sPtr[a] = s; s += sDeg[a]; }
        sPtr[A_ATOMS] = s;
    }
    __syncthreads();
    const int NB = (cnt + EB - 1) / EB;
    // ordered CSR fill + per-batch windows (thread a owns its own segment)
    if (tid < A_ATOMS) {
        const int ps = sPtr[tid];
        int pos = ps;
        for (int i = 0; i < cnt; ++i) {
            unsigned pe = sEdge[i];
            int a0l = (pe >> 6) & 63, a1l = pe & 63;
            if (a0l == tid) sCsr[pos++] = (unsigned short)((a1l << 10) | i);
            if (a1l == tid) sCsr[pos++] = (unsigned short)((a0l << 10) | i);
        }
        // windows: sWin[a][b] = first entry index with edge >= b*EB
        int p = ps;
        for (int b = 0; b <= NB; ++b) {
            const int lim = b * EB;
            while (p < pos && (int)(sCsr[p] & 1023) < lim) ++p;
            sWin[tid * (NBMAX + 1) + b] = (unsigned short)p;
        }
    }

    for (int l = 0; l < NLAYERS; ++l) {
        __syncthreads();
        // ---- M1: sB = r @ Wn + bn
        {
            f32x4 acc[3][2];
            mfma_dense8(sR, WT + ((size_t)(0 * 4 + l) << 16), acc, lane, wv);
            mfma_wb8<0>(acc, sB, bn + l * D, lane, wv);
        }
        __syncthreads();
        // ---- edge phase: balanced 2-barrier pipeline, batches of 64
        float4 agg[5];
#pragma unroll
        for (int k = 0; k < 5; ++k) agg[k] = make_float4(0.f, 0.f, 0.f, 0.f);
        {
            // per-layer hoisted fragments: P4 (n-tiles 2wv, 2wv+1) and X2 (t-tile ttx)
            const bshort8 bf0 = *(const bshort8*)&WT2[(size_t)l * 8192 + ((2 * wv + 0) * 16 + fr) * 32 + g8];
            const bshort8 bf1 = *(const bshort8*)&WT2[(size_t)l * 8192 + ((2 * wv + 1) * 16 + fr) * 32 + g8];
            const float bb0 = be2[l * D + (2 * wv + 0) * 16 + fr];
            const float bb1 = be2[l * D + (2 * wv + 1) * 16 + fr];
            const bshort8 bfX = *(const bshort8*)&We1T[(size_t)l * 1024 + (ttx * 16 + fr) * 32 + g8];
            const float bbX = be1[l * NG + ttx * 16 + fr];

            // prologue: X2(0) -> sHb[0] (all 8 waves; waves wv and wv+4 share mtx)
            if (NB > 0) {
                const float dd = sDall[mtx * 16 + fr];
                union { bshort8 v; unsigned short h[8]; } ua;
#pragma unroll
                for (int j = 0; j < 8; ++j) {
                    const float u = dd - (float)(g8 + j);
                    ua.h[j] = (unsigned short)f2b(expf(-0.5f * u * u));
                }
                f32x4 c = (f32x4){0.f, 0.f, 0.f, 0.f};
                c = __builtin_amdgcn_mfma_f32_16x16x32_bf16(ua.v, bfX, c, 0, 0, 0);
#pragma unroll
                for (int reg = 0; reg < 4; ++reg) {
                    const int erow = mtx * 16 + fg * 4 + reg;
                    sHb[0][erow * SHBP + ttx * 16 + fr] = f2b(sspf(c[reg] + bbX));
                }
            }
            __syncthreads();
            for (int b = 0; b < NB; ++b) {
                const int base = b * EB;
                // ---- phase1: P4(b) then X2(b+1), every wave does both
                {
                    const short* __restrict__ hb = sHb[b & 1];
#pragma unroll
                    for (int mt = 0; mt < 4; ++mt) {
                        union { bshort8 v; short4 s[2]; } af;
                        af.s[0] = *(const short4*)&hb[(mt * 16 + fr) * SHBP + g8];
                        af.s[1] = *(const short4*)&hb[(mt * 16 + fr) * SHBP + g8 + 4];
                        f32x4 c0 = (f32x4){0.f, 0.f, 0.f, 0.f};
                        c0 = __builtin_amdgcn_mfma_f32_16x16x32_bf16(af.v, bf0, c0, 0, 0, 0);
                        f32x4 c1 = (f32x4){0.f, 0.f, 0.f, 0.f};
                        c1 = __builtin_amdgcn_mfma_f32_16x16x32_bf16(af.v, bf1, c1, 0, 0, 0);
#pragma unroll
                        for (int reg = 0; reg < 4; ++reg) {
                            const int erow = mt * 16 + fg * 4 + reg;
                            sEFs[erow * SEFP + (2 * wv + 0) * 16 + fr] = f2b(c0[reg] + bb0);
                            sEFs[erow * SEFP + (2 * wv + 1) * 16 + fr] = f2b(c1[reg] + bb1);
                        }
                    }
                }
                if (b + 1 < NB) {
                    short* __restrict__ hb = sHb[(b + 1) & 1];
                    const float dd = sDall[(b + 1) * EB + mtx * 16 + fr];
                    union { bshort8 v; unsigned short h[8]; } ua;
#pragma unroll
                    for (int j = 0; j < 8; ++j) {
                        const float u = dd - (float)(g8 + j);
                        ua.h[j] = (unsigned short)f2b(expf(-0.5f * u * u));
                    }
                    f32x4 c = (f32x4){0.f, 0.f, 0.f, 0.f};
                    c = __builtin_amdgcn_mfma_f32_16x16x32_bf16(ua.v, bfX, c, 0, 0, 0);
#pragma unroll
                    for (int reg = 0; reg < 4; ++reg) {
                        const int erow = mtx * 16 + fg * 4 + reg;
                        hb[erow * SHBP + ttx * 16 + fr] = f2b(sspf(c[reg] + bbX));
                    }
                }
                __syncthreads();
                // ---- phase2: P5 counted gathers (wave owns rows 5wv..5wv+4)
#pragma unroll
                for (int k = 0; k < 5; ++k) {
                    const int row = wv * 5 + k;
                    const int st = (int)sWin[row * (NBMAX + 1) + b];
                    const int en = (int)sWin[row * (NBMAX + 1) + b + 1];
                    for (int i = st; i < en; ++i) {
                        const int ent = (int)sCsr[i];
                        const int e = ent & 1023, src = ent >> 10;
                        const short4 f4 = *(const short4*)&sEFs[(e - base) * SEFP + c4];
                        const float4 r4 = *(const float4*)&sB[src * SRP + c4];
                        agg[k].x = fmaf(b2f(f4.x), r4.x, agg[k].x);
                        agg[k].y = fmaf(b2f(f4.y), r4.y, agg[k].y);
                        agg[k].z = fmaf(b2f(f4.z), r4.z, agg[k].z);
                        agg[k].w = fmaf(b2f(f4.w), r4.w, agg[k].w);
                    }
                }
                __syncthreads();
            }
        }
        // agg -> sB (rn dead)
#pragma unroll
        for (int k = 0; k < 5; ++k)
            *(float4*)&sB[(wv * 5 + k) * SRP + c4] = agg[k];
        __syncthreads();
        // ---- M2: sB = ssp(agg @ Wu1 + bu1)  (in-place: sync between acc and wb)
        {
            f32x4 acc[3][2];
            mfma_dense8(sB, WT + ((size_t)(1 * 4 + l) << 16), acc, lane, wv);
            __syncthreads();
            mfma_wb8<1>(acc, sB, bu1 + l * D, lane, wv);
        }
        __syncthreads();
        // ---- M3: sR += t @ Wu2 + bu2
        {
            f32x4 acc[3][2];
            mfma_dense8(sB, WT + ((size_t)(2 * 4 + l) << 16), acc, lane, wv);
            mfma_wb8<2>(acc, sR, bu2 + l * D, lane, wv);
        }
    }
    __syncthreads();
    if (tid < D) {
        float s = 0.f;
#pragma unroll
        for (int a = 0; a < A_ATOMS; ++a) s += sR[a * SRP + tid];
        conf_fp[conf * D + tid] = s;
    }
}

// ---------------- per-conformer molecular MLP + Boltzmann-weighted reduce ----------------
__global__ __launch_bounds__(512) void k_mol(
    const float* __restrict__ conf_fp,
    const float* __restrict__ Wm1, const float* __restrict__ bm1,
    const float* __restrict__ Wm2, const float* __restrict__ bm2,
    const float* __restrict__ boltz, float* __restrict__ mol_fp)
{
    __shared__ float cf[D];
    __shared__ float t[H_MOL];
    const int conf = blockIdx.x;
    const int tid = threadIdx.x;
    if (tid < D) cf[tid] = conf_fp[conf * D + tid];
    __syncthreads();
    if (tid < H_MOL) {
        float s = bm1[tid];
        for (int k = 0; k < D; k += 4) {
            const float4 v = *(const float4*)&cf[k];
            s = fmaf(v.x, Wm1[(k + 0) * H_MOL + tid], s);
            s = fmaf(v.y, Wm1[(k + 1) * H_MOL + tid], s);
            s = fmaf(v.z, Wm1[(k + 2) * H_MOL + tid], s);
            s = fmaf(v.w, Wm1[(k + 3) * H_MOL + tid], s);
        }
        t[tid] = sspf(s);
    }
    __syncthreads();
    {
        const int m = tid;
        float s = bm2[m];
        for (int h = 0; h < H_MOL; h += 4) {
            const float4 v = *(const float4*)&t[h];
            s = fmaf(v.x, Wm2[(h + 0) * MOLB + m], s);
            s = fmaf(v.y, Wm2[(h + 1) * MOLB + m], s);
            s = fmaf(v.z, Wm2[(h + 2) * MOLB + m], s);
            s = fmaf(v.w, Wm2[(h + 3) * MOLB + m], s);
        }
        atomicAdd(&mol_fp[(conf / N_CONFS_PER) * MOLB + m], s * boltz[conf]);
    }
}

// ---------------- final readout MLP + sigmoid ----------------
__global__ __launch_bounds__(256) void k_final(
    const float* __restrict__ mol_fp,
    const float* __restrict__ Wr1, const float* __restrict__ br1,
    const float* __restrict__ Wr2, const float* __restrict__ br2,
    float* __restrict__ out)
{
    __shared__ float mf[MOLB];
    __shared__ float t2[D];
    __shared__ float red[4];
    const int mol = blockIdx.x, tid = threadIdx.x;
    mf[tid]       = mol_fp[mol * MOLB + tid];
    mf[tid + 256] = mol_fp[mol * MOLB + tid + 256];
    __syncthreads();
    {
        float s = br1[tid];
        for (int k = 0; k < MOLB; k += 4) {
            const float4 v = *(const float4*)&mf[k];
            s = fmaf(v.x, Wr1[(k + 0) * D + tid], s);
            s = fmaf(v.y, Wr1[(k + 1) * D + tid], s);
            s = fmaf(v.z, Wr1[(k + 2) * D + tid], s);
            s = fmaf(v.w, Wr1[(k + 3) * D + tid], s);
        }
        t2[tid] = sspf(s);
    }
    __syncthreads();
    float p = t2[tid] * Wr2[tid];
#pragma unroll
    for (int o = 32; o > 0; o >>= 1) p += __shfl_down(p, o);
    if ((tid & 63) == 0) red[tid >> 6] = p;
    __syncthreads();
    if (tid == 0) {
        float logit = red[0] + red[1] + red[2] + red[3] + br2[0];
        out[mol] = 1.f / (1.f + expf(-logit));
    }
}

extern "C" void kernel_launch(void* const* d_in, const int* in_sizes, int n_in,
                              void* d_out, int out_size, void* d_ws, size_t ws_size,
                              hipStream_t stream)
{
    const int*   z     = (const int*)d_in[0];
    const float* xyz   = (const float*)d_in[1];
    const int*   nbr   = (const int*)d_in[2];
    const float* boltz = (const float*)d_in[3];
    const float* emb   = (const float*)d_in[4];
    const float* We1   = (const float*)d_in[5];
    const float* be1   = (const float*)d_in[6];
    const float* We2   = (const float*)d_in[7];
    const float* be2   = (const float*)d_in[8];
    const float* Wn    = (const float*)d_in[9];
    const float* bn    = (const float*)d_in[10];
    const float* Wu1   = (const float*)d_in[11];
    const float* bu1   = (const float*)d_in[12];
    const float* Wu2   = (const float*)d_in[13];
    const float* bu2   = (const float*)d_in[14];
    const float* Wm1   = (const float*)d_in[15];
    const float* bm1   = (const float*)d_in[16];
    const float* Wm2   = (const float*)d_in[17];
    const float* bm2   = (const float*)d_in[18];
    const float* Wr1   = (const float*)d_in[19];
    const float* br1   = (const float*)d_in[20];
    const float* Wr2   = (const float*)d_in[21];
    const float* br2   = (const float*)d_in[22];

    char* ws = (char*)d_ws;
    unsigned* cursors        = (unsigned*)ws;                   // 2560 B
    float*    mol_fp         = (float*)(ws + 2560);             // 131072 B -> 133632
    unsigned* esort          = (unsigned*)(ws + 133632);        // 2621440 B -> 2755072
    float*    conf_fp        = (float*)(ws + 2755072);          // 655360 B -> 3410432
    __hip_bfloat16* WT       = (__hip_bfloat16*)(ws + 3410432); // 1572864 B -> 4983296
    __hip_bfloat16* WT2      = (__hip_bfloat16*)(ws + 4983296); // 65536 B -> 5048832
    __hip_bfloat16* We1T     = (__hip_bfloat16*)(ws + 5048832); // 8192 B -> 5057024

    hipMemsetAsync(cursors, 0, 2560 + 131072, stream);          // cursors + mol_fp
    k_prep<<<3072, 256, 0, stream>>>(Wn, Wu1, Wu2, WT);
    k_prep2<<<144, 256, 0, stream>>>(We2, We1, WT2, We1T);
    k_scatter<<<(N_EDGES + 255) / 256, 256, 0, stream>>>(nbr, cursors, esort);
    k_main<<<N_CONFS, TPB, 0, stream>>>(z, xyz, emb, be1, be2, bn,
                                        bu1, bu2, WT, WT2, We1T, cursors, esort, conf_fp);
    k_mol<<<N_CONFS, 512, 0, stream>>>(conf_fp, Wm1, bm1, Wm2, bm2, boltz, mol_fp);
    k_final<<<N_MOLS, 256, 0, stream>>>(mol_fp, Wr1, br1, Wr2, br2, (float*)d_out);
}